// Round 2
// baseline (68.756 us; speedup 1.0000x reference)
//
#include <hip/hip_runtime.h>
#include <hip/hip_bf16.h>

// out[b,w] = relu(sqrt(max(||x_b||^2 + ||w_w||^2 - 2*x_b.w_w, 0)) / sqrt(512))
// M=8192, N=4096, K=512. bf16 MFMA NT-GEMM, 256x256 tile, 8-phase counted-vmcnt
// pipeline (4 phases/K-tile, 2 K-tile LDS parity buffers).

typedef __bf16 bf16x8 __attribute__((ext_vector_type(8)));
typedef float f32x4 __attribute__((ext_vector_type(4)));

#define K_DIM 512
#define NT 8  // K_DIM / 64
#define INV_SCALE 0.04419417382415922f  // 1/22.627417

__device__ __forceinline__ ushort f2bf(float f) {
  __hip_bfloat16 h = __float2bfloat16(f);
  return __builtin_bit_cast(ushort, h);
}

// fp32 -> bf16 convert + row sum of squares. One 128-thread block per row.
__global__ __launch_bounds__(128) void convert_kernel(
    const float* __restrict__ x, const float* __restrict__ w,
    ushort* __restrict__ xb, ushort* __restrict__ wb,
    float* __restrict__ xsq, float* __restrict__ wsq, int M) {
  int b = blockIdx.x;
  const float* src; ushort* dst; float* sq; int row;
  if (b < M) { src = x; dst = xb; sq = xsq; row = b; }
  else       { src = w; dst = wb; sq = wsq; row = b - M; }
  int t = threadIdx.x;
  float4 v = reinterpret_cast<const float4*>(src + (size_t)row * K_DIM)[t];
  ushort4 p;
  p.x = f2bf(v.x); p.y = f2bf(v.y); p.z = f2bf(v.z); p.w = f2bf(v.w);
  reinterpret_cast<ushort4*>(dst + (size_t)row * K_DIM)[t] = p;
  float s = v.x * v.x + v.y * v.y + v.z * v.z + v.w * v.w;
#pragma unroll
  for (int o = 32; o > 0; o >>= 1) s += __shfl_down(s, o, 64);
  __shared__ float red[2];
  if ((t & 63) == 0) red[t >> 6] = s;
  __syncthreads();
  if (t == 0) sq[row] = red[0] + red[1];
}

// LDS: 8 slots of [256 rows][32 cols] bf16 = 16 KB each, 128 KiB total.
// slot(par, kh, ab) : par = K-tile parity, kh = K-half (32 cols), ab: 0=A 1=B.
// ds_read fragment pattern covers a contiguous 1KB block with lane-distinct
// 16B chunks -> bank-conflict-free by construction (no swizzle needed).
__global__ __launch_bounds__(512, 2) void gemm_dist_kernel(
    const ushort* __restrict__ xb, const ushort* __restrict__ wb,
    const float* __restrict__ xsq, const float* __restrict__ wsq,
    float* __restrict__ out, int M, int N) {
  __shared__ ushort lds[8 * 8192];  // 128 KiB

  const int ntN = N >> 8;                 // 16
  const int nwg = gridDim.x;              // 512 (divisible by 8)
  const int bid = blockIdx.x;
  const int swz = (bid & 7) * (nwg >> 3) + (bid >> 3);  // XCD-aware, bijective
  const int tR = swz / ntN, tC = swz - tR * ntN;
  const int rowA0 = tR << 8, rowB0 = tC << 8;

  const int tid = threadIdx.x;
  const int wid = tid >> 6, lane = tid & 63;
  const int wr = wid >> 2, wc = wid & 3;  // 2 x 4 wave grid, wave out = 128x64
  const int l15 = lane & 15, l4 = lane >> 4;

  // ds_read base offsets within a slot (ushort units):
  //   A row = wr*128 + c*64 + i*16 + l15, col = l4*8  (slot row stride 32)
  const int aoff = (wr << 7) * 32 + l15 * 32 + l4 * 8;
  const int boff = (wc << 6) * 32 + l15 * 32 + l4 * 8;

  // Stage source pointers: load c in {0,1}: idx = c*512 + tid,
  //   row = idx>>2, col = (idx&3)*8 of a [256][32] half-tile.
  const ushort* gA[2]; const ushort* gB[2];
#pragma unroll
  for (int c = 0; c < 2; ++c) {
    const int idx = c * 512 + tid;
    gA[c] = xb + (size_t)(rowA0 + (idx >> 2)) * K_DIM + ((idx & 3) << 3);
    gB[c] = wb + (size_t)(rowB0 + (idx >> 2)) * K_DIM + ((idx & 3) << 3);
  }

  f32x4 acc[8][4] = {};

#define SLOT(par, kh, ab) (&lds[((((par)*2 + (kh)) * 2) + (ab)) * 8192])

// Stage one half-tile (2 x global_load_lds, 16B/lane) for K-tile st, K-half kh.
// LDS dest is wave-uniform (slot + c*4096 + wid*512); global src is per-lane.
#define STAGE(st, kh, ab) do {                                                 \
    if ((st) < NT) {                                                           \
      const ushort* g0 = ((ab) ? gB[0] : gA[0]) + (st) * 64 + (kh) * 32;       \
      const ushort* g1 = ((ab) ? gB[1] : gA[1]) + (st) * 64 + (kh) * 32;       \
      ushort* l0 = SLOT((st) & 1, kh, ab) + wid * 512;                         \
      __builtin_amdgcn_global_load_lds(                                        \
          (const __attribute__((address_space(1))) void*)g0,                   \
          (__attribute__((address_space(3))) void*)l0, 16, 0, 0);              \
      __builtin_amdgcn_global_load_lds(                                        \
          (const __attribute__((address_space(1))) void*)g1,                   \
          (__attribute__((address_space(3))) void*)(l0 + 4096), 16, 0, 0);     \
    } } while (0)

// One phase: ds_read 8 frags, issue 1 half-tile stage, barrier, wait own
// ds_reads, 16 MFMA under setprio, optional counted vmcnt, barrier.
#define PHASE(par, kh, c, stT, stKh, stAb, VM) do {                            \
    const ushort* As = SLOT(par, kh, 0);                                       \
    const ushort* Bs = SLOT(par, kh, 1);                                       \
    bf16x8 af[4], bg[4];                                                       \
    _Pragma("unroll")                                                          \
    for (int i = 0; i < 4; ++i)                                                \
      af[i] = *reinterpret_cast<const bf16x8*>(As + aoff + (c) * 2048 + i * 512); \
    _Pragma("unroll")                                                          \
    for (int j = 0; j < 4; ++j)                                                \
      bg[j] = *reinterpret_cast<const bf16x8*>(Bs + boff + j * 512);           \
    STAGE(stT, stKh, stAb);                                                    \
    asm volatile("s_barrier" : : : "memory");                                  \
    asm volatile("s_waitcnt lgkmcnt(0)" : : : "memory");                       \
    __builtin_amdgcn_sched_barrier(0);                                         \
    __builtin_amdgcn_s_setprio(1);                                             \
    _Pragma("unroll")                                                          \
    for (int i = 0; i < 4; ++i)                                                \
      _Pragma("unroll")                                                        \
      for (int j = 0; j < 4; ++j)                                              \
        acc[(c) * 4 + i][j] = __builtin_amdgcn_mfma_f32_16x16x32_bf16(         \
            af[i], bg[j], acc[(c) * 4 + i][j], 0, 0, 0);                       \
    __builtin_amdgcn_s_setprio(0);                                             \
    if ((VM) == 4)      asm volatile("s_waitcnt vmcnt(4)" : : : "memory");     \
    else if ((VM) == 0) asm volatile("s_waitcnt vmcnt(0)" : : : "memory");     \
    asm volatile("s_barrier" : : : "memory");                                  \
  } while (0)

  // Prologue: issue k0[0], k1[0], k0[1] (12 loads); wait tile0 landed (leave
  // k0[1]'s 4 in flight); publish.
  STAGE(0, 0, 0); STAGE(0, 0, 1);
  STAGE(0, 1, 0); STAGE(0, 1, 1);
  STAGE(1, 0, 0); STAGE(1, 0, 1);
  asm volatile("s_waitcnt vmcnt(4)" : : : "memory");
  asm volatile("s_barrier" : : : "memory");

  // Ledger (steady state), per tile t:
  //  P0: compute(k0,c0), stage A-k1[t+1]   (slot freed at t-1 P3's barrier)
  //  P1: compute(k0,c1), stage B-k1[t+1]
  //  P2: compute(k1,c0), stage A-k0[t+2]   (slot freed at this tile P1's barrier)
  //  P3: compute(k1,c1), stage B-k0[t+2], vmcnt(4) -> all of tile t+1 landed,
  //      leaves k0[t+2] (4 loads) in flight; barrier publishes.
#pragma unroll 2
  for (int t = 0; t < NT; ++t) {
    const int par = t & 1;
    const int vm = (t < NT - 2) ? 4 : 0;  // drain near tail (skipped stages)
    PHASE(par, 0, 0, t + 1, 1, 0, -1);
    PHASE(par, 0, 1, t + 1, 1, 1, -1);
    PHASE(par, 1, 0, t + 2, 0, 0, -1);
    PHASE(par, 1, 1, t + 2, 0, 1, vm);
  }

  // Epilogue. Verified C/D mapping: col = lane&15, row = (lane>>4)*4 + reg.
  const int rBase = rowA0 + (wr << 7) + (l4 << 2);
  const int cBase = rowB0 + (wc << 6) + l15;
  float wq[4];
#pragma unroll
  for (int j = 0; j < 4; ++j) wq[j] = wsq[cBase + (j << 4)];

#pragma unroll
  for (int c = 0; c < 2; ++c)
#pragma unroll
    for (int i = 0; i < 4; ++i)
#pragma unroll
      for (int r = 0; r < 4; ++r) {
        const int row = rBase + (c << 6) + (i << 4) + r;
        const float xq = xsq[row];
        const size_t ro = (size_t)row * (size_t)N;
#pragma unroll
        for (int j = 0; j < 4; ++j) {
          float v = xq + wq[j] - 2.0f * acc[c * 4 + i][j][r];
          out[ro + cBase + (j << 4)] = sqrtf(fmaxf(v, 0.0f)) * INV_SCALE;
        }
      }
#undef PHASE
#undef STAGE
#undef SLOT
}

extern "C" void kernel_launch(void* const* d_in, const int* in_sizes, int n_in,
                              void* d_out, int out_size, void* d_ws, size_t ws_size,
                              hipStream_t stream) {
  const float* x = (const float*)d_in[0];   // (M, 512) fp32
  const float* w = (const float*)d_in[1];   // (N, 512) fp32
  const int M = in_sizes[0] / K_DIM;        // 8192
  const int N = in_sizes[1] / K_DIM;        // 4096
  float* out = (float*)d_out;

  char* ws = (char*)d_ws;
  ushort* xb = (ushort*)ws;
  ushort* wb = (ushort*)(ws + (size_t)M * K_DIM * 2);
  float* xsq = (float*)(ws + (size_t)M * K_DIM * 2 + (size_t)N * K_DIM * 2);
  float* wsq = xsq + M;

  convert_kernel<<<M + N, 128, 0, stream>>>(x, w, xb, wb, xsq, wsq, M);

  dim3 grid((M >> 8) * (N >> 8));  // 32 * 16 = 512
  gemm_dist_kernel<<<grid, 512, 0, stream>>>(xb, wb, xsq, wsq, out, M, N);
}